// Round 3
// baseline (157.463 us; speedup 1.0000x reference)
//
#include <hip/hip_runtime.h>

#define NN 64
#define CC 128
#define TT 2048
#define SS 9
#define PAD 4
#define EPSF 1e-5f
#define TL 32                 // t columns per block
#define ROWS (CC + 2 * PAD)   // 136 staged rows
#define STRIDE (TL + 1)       // 33: odd -> conflict-free c-per-lane reads
#define NB 16                 // stat buckets

// ---------------------------------------------------------------------------
// K1: stage shifted tile -> conv -> raw conv to out (float4 stores)
//     + per-thread sum/sumsq -> pair-combined -> bucketed global atomics.
// Core staging/conv/stats identical to the verified 155 us baseline; only the
// final store loop changed from 16x scalar (4 B/lane) to 4x float4 (16 B/lane).
// ---------------------------------------------------------------------------
__global__ __launch_bounds__(256, 8) void conv_store_stats(
    const float* __restrict__ x, const float* __restrict__ cw,
    float* __restrict__ buckets, float* __restrict__ out)
{
    __shared__ float ls[ROWS * STRIDE];   // 17952 B
    __shared__ float sred[512];           // +2048 B -> 20000 B, 8 blocks/CU

    const int n     = blockIdx.y;
    const int t0    = blockIdx.x * TL;
    const int tid   = threadIdx.x;
    const int lane  = tid & 63;
    const int wid   = tid >> 6;
    const int col   = lane & 31;
    const int rhalf = lane >> 5;          // two 32-lane rows per wave instr
    const float* __restrict__ xn = x + (size_t)n * CC * TT;

    // ---- stage: ls[c2+4][j] = xs[n, c2, t0+j] (pre-shifted, zero-padded) ----
#pragma unroll
    for (int i = 0; i < 17; ++i) {        // 34 rows per wave, 2 per iter
        const int r  = wid * 34 + 2 * i + rhalf;
        const int c2 = r - PAD;
        float v = 0.f;
        if (c2 >= 0 && c2 < CC) {
            const int sh = (c2 % SS) - PAD;
            const int t  = t0 + col - sh;
            if (t >= 0 && t < TT) v = xn[c2 * TT + t];
        }
        ls[r * STRIDE + col] = v;
    }

    const int c  = tid & (CC - 1);        // fixed output channel per thread
    const int jb = (tid >> 7) * (TL / 2); // 0 or 16
    float wv[SS];
#pragma unroll
    for (int s = 0; s < SS; ++s) wv[s] = cw[c * SS + s];

    __syncthreads();

    // ---- conv: rows c..c+8, conflict-free (STRIDE odd, c = lane) ----
    const int base = c * STRIDE + jb;
    float res[TL / 2];
    float s1 = 0.f, s2 = 0.f;
#pragma unroll
    for (int j = 0; j < TL / 2; ++j) {
        float acc = 0.f;
#pragma unroll
        for (int s = 0; s < SS; ++s)
            acc = fmaf(wv[s], ls[base + s * STRIDE + j], acc);
        res[j] = acc;
        s1 += acc;
        s2 = fmaf(acc, acc, s2);
    }

    // ---- transpose res into ls + stage stats partials ----
    __syncthreads();                      // conv reads done; safe to overwrite
#pragma unroll
    for (int j = 0; j < TL / 2; ++j)
        ls[c * STRIDE + jb + j] = res[j];
    sred[tid]       = s1;
    sred[256 + tid] = s2;
    __syncthreads();

    // ---- bucketed atomics: pair (tid, tid+128) combined -> 1 add per (blk,c) ----
    if (tid < CC) {
        float* bs = buckets + ((blockIdx.x + blockIdx.y) & (NB - 1)) * 2 * CC;
        atomicAdd(&bs[tid],      sred[tid]       + sred[tid + 128]);
        atomicAdd(&bs[CC + tid], sred[256 + tid] + sred[256 + tid + 128]);
    }

    // ---- raw conv -> out, float4 coalesced (1024 float4 = 128 rows x 8) ----
    float* __restrict__ on = out + (size_t)n * CC * TT + t0;
#pragma unroll
    for (int k = 0; k < 4; ++k) {
        const int f   = tid + 256 * k;
        const int row = f >> 3;
        const int q   = (f & 7) * 4;      // 16B-aligned (t0 mult of 32)
        float4 v;
        v.x = ls[row * STRIDE + q];
        v.y = ls[row * STRIDE + q + 1];
        v.z = ls[row * STRIDE + q + 2];
        v.w = ls[row * STRIDE + q + 3];
        *reinterpret_cast<float4*>(on + (size_t)row * TT + q) = v;
    }
}

// ---------------------------------------------------------------------------
// K2: fold the 16 stat buckets once -> per-channel g,b (1 KB) in workspace.
// One block; removes the 32-load fold from every block of the stream kernel.
// ---------------------------------------------------------------------------
__global__ void stats_fold(
    const float* __restrict__ buckets, const float* __restrict__ gamma,
    const float* __restrict__ beta, float* __restrict__ gb)
{
    const int c = threadIdx.x;
    if (c < CC) {
        float t1 = 0.f, t2 = 0.f;
#pragma unroll
        for (int k = 0; k < NB; ++k) {
            t1 += buckets[k * 2 * CC + c];
            t2 += buckets[k * 2 * CC + CC + c];
        }
        const float inv_cnt = 1.0f / (float)(NN * TT);
        const float mean = t1 * inv_cnt;
        const float var  = t2 * inv_cnt - mean * mean;
        const float inv  = rsqrtf(var + EPSF);
        const float g = gamma[c] * inv;
        gb[c]      = g;
        gb[CC + c] = beta[c] - mean * g;
    }
}

// ---------------------------------------------------------------------------
// K3: pure-stream normalize + ReLU. 2048 blocks x 4 rows; 8 independent
// float4 RMWs per thread (all loads issued before any store -> deep MLP).
// Replaces the old 8192-block / 2-RMW kernel that ran at ~1.2 TB/s.
// ---------------------------------------------------------------------------
__global__ __launch_bounds__(256, 8) void norm_relu_vec(
    const float* __restrict__ gb, float* __restrict__ out)
{
    const int r0  = blockIdx.x * 4;       // 4 consecutive rows of NN*CC=8192
    const int tid = threadIdx.x;
    float4* __restrict__ o4 = (float4*)out;

    float g[4], b[4];
#pragma unroll
    for (int k = 0; k < 4; ++k) {         // block-uniform scalar loads
        const int c = (r0 + k) & (CC - 1);
        g[k] = gb[c];
        b[k] = gb[CC + c];
    }

    float4 v[8];
#pragma unroll
    for (int k = 0; k < 4; ++k) {         // issue all 8 loads first
        const size_t base = (size_t)(r0 + k) * (TT / 4);
        v[2 * k]     = o4[base + tid];
        v[2 * k + 1] = o4[base + tid + 256];
    }
#pragma unroll
    for (int k = 0; k < 4; ++k) {
#pragma unroll
        for (int j = 0; j < 2; ++j) {
            float4& w = v[2 * k + j];
            w.x = fmaf(w.x, g[k], b[k]);
            w.y = fmaf(w.y, g[k], b[k]);
            w.z = fmaf(w.z, g[k], b[k]);
            w.w = fmaf(w.w, g[k], b[k]);
            w.x = w.x > 0.f ? w.x : 0.f;
            w.y = w.y > 0.f ? w.y : 0.f;
            w.z = w.z > 0.f ? w.z : 0.f;
            w.w = w.w > 0.f ? w.w : 0.f;
        }
    }
#pragma unroll
    for (int k = 0; k < 4; ++k) {
        const size_t base = (size_t)(r0 + k) * (TT / 4);
        o4[base + tid]       = v[2 * k];
        o4[base + tid + 256] = v[2 * k + 1];
    }
}

extern "C" void kernel_launch(void* const* d_in, const int* in_sizes, int n_in,
                              void* d_out, int out_size, void* d_ws, size_t ws_size,
                              hipStream_t stream)
{
    const float* x     = (const float*)d_in[0];
    const float* cw    = (const float*)d_in[1];
    const float* gamma = (const float*)d_in[2];
    const float* beta  = (const float*)d_in[3];
    float* out     = (float*)d_out;
    float* buckets = (float*)d_ws;                    // [NB][2][CC] = 16 KB
    float* gb      = (float*)d_ws + NB * 2 * CC;      // [2][CC]     =  1 KB

    hipMemsetAsync(buckets, 0, (size_t)NB * 2 * CC * sizeof(float), stream);

    dim3 grid1(TT / TL, NN);              // 64 x 64 = 4096 blocks
    conv_store_stats<<<grid1, 256, 0, stream>>>(x, cw, buckets, out);
    stats_fold<<<1, 128, 0, stream>>>(buckets, gamma, beta, gb);
    norm_relu_vec<<<(NN * CC) / 4, 256, 0, stream>>>(gb, out);
}

// Round 4
// 153.051 us; speedup vs baseline: 1.0288x; 1.0288x over previous
//
#include <hip/hip_runtime.h>

#define NN 64
#define CC 128
#define TT 2048
#define SS 9
#define PAD 4
#define EPSF 1e-5f
#define TL 32                 // t columns per block
#define ROWS (CC + 2 * PAD)   // 136 staged rows
#define STRIDE (TL + 1)       // 33: odd -> conflict-free c-per-lane reads
#define NB 16                 // stat buckets

// ---------------------------------------------------------------------------
// Recompute strategy across a kernel boundary (the legal device-wide barrier):
//   K1: stage x -> conv -> stats atomics only   (no out write, no res[])
//   K2: re-stage x (L3-resident) -> conv again -> fold buckets -> norm ->
//       transpose -> float4 store
// Deletes the raw-conv HBM round trip (write 64 MB + read 64 MB) entirely.
// Ideal HBM traffic: read x once (62 MB) + write out once (64 MB).
// ---------------------------------------------------------------------------

// K1: conv for stats only.
__global__ __launch_bounds__(256, 8) void conv_stats(
    const float* __restrict__ x, const float* __restrict__ cw,
    float* __restrict__ buckets)
{
    __shared__ float ls[ROWS * STRIDE];   // 17952 B
    __shared__ float sred[512];           // +2048 B -> 20000 B, 8 blocks/CU

    const int n     = blockIdx.y;
    const int t0    = blockIdx.x * TL;
    const int tid   = threadIdx.x;
    const int lane  = tid & 63;
    const int wid   = tid >> 6;
    const int col   = lane & 31;
    const int rhalf = lane >> 5;          // two 32-lane rows per wave instr
    const float* __restrict__ xn = x + (size_t)n * CC * TT;

    // ---- stage: ls[c2+4][j] = xs[n, c2, t0+j] (pre-shifted, zero-padded) ----
#pragma unroll
    for (int i = 0; i < 17; ++i) {        // 34 rows per wave, 2 per iter
        const int r  = wid * 34 + 2 * i + rhalf;
        const int c2 = r - PAD;
        float v = 0.f;
        if (c2 >= 0 && c2 < CC) {
            const int sh = (c2 % SS) - PAD;
            const int t  = t0 + col - sh;
            if (t >= 0 && t < TT) v = xn[c2 * TT + t];
        }
        ls[r * STRIDE + col] = v;
    }

    const int c  = tid & (CC - 1);        // fixed output channel per thread
    const int jb = (tid >> 7) * (TL / 2); // 0 or 16
    float wv[SS];
#pragma unroll
    for (int s = 0; s < SS; ++s) wv[s] = cw[c * SS + s];

    __syncthreads();

    // ---- conv: rows c..c+8, conflict-free (STRIDE odd, c = lane) ----
    const int base = c * STRIDE + jb;
    float s1 = 0.f, s2 = 0.f;
#pragma unroll
    for (int j = 0; j < TL / 2; ++j) {
        float acc = 0.f;
#pragma unroll
        for (int s = 0; s < SS; ++s)
            acc = fmaf(wv[s], ls[base + s * STRIDE + j], acc);
        s1 += acc;
        s2 = fmaf(acc, acc, s2);
    }

    // ---- pair-combine partials -> 1 atomic per (block, channel) ----
    sred[tid]       = s1;
    sred[256 + tid] = s2;
    __syncthreads();
    if (tid < CC) {
        float* bs = buckets + ((blockIdx.x + blockIdx.y) & (NB - 1)) * 2 * CC;
        atomicAdd(&bs[tid],      sred[tid]       + sred[tid + 128]);
        atomicAdd(&bs[CC + tid], sred[256 + tid] + sred[256 + tid + 128]);
    }
}

// K2: re-stage (L3 hit) -> conv -> fold stats -> normalize -> float4 store.
__global__ __launch_bounds__(256, 8) void conv_norm_store(
    const float* __restrict__ x, const float* __restrict__ cw,
    const float* __restrict__ buckets, const float* __restrict__ gamma,
    const float* __restrict__ beta, float* __restrict__ out)
{
    __shared__ float ls[ROWS * STRIDE];   // 17952 B -> 8 blocks/CU

    const int n     = blockIdx.y;
    const int t0    = blockIdx.x * TL;
    const int tid   = threadIdx.x;
    const int lane  = tid & 63;
    const int wid   = tid >> 6;
    const int col   = lane & 31;
    const int rhalf = lane >> 5;
    const float* __restrict__ xn = x + (size_t)n * CC * TT;

    const int c  = tid & (CC - 1);
    const int jb = (tid >> 7) * (TL / 2);

    // ---- fold 16 buckets (L2-resident 16 KB, coalesced) -> g,b per thread ----
    float t1 = 0.f, t2 = 0.f;
#pragma unroll
    for (int k = 0; k < NB; ++k) {
        t1 += buckets[k * 2 * CC + c];
        t2 += buckets[k * 2 * CC + CC + c];
    }
    const float inv_cnt = 1.0f / (float)(NN * TT);
    const float mean = t1 * inv_cnt;
    const float var  = t2 * inv_cnt - mean * mean;
    const float inv  = rsqrtf(var + EPSF);
    const float g = gamma[c] * inv;
    const float b = beta[c] - mean * g;

    float wv[SS];
#pragma unroll
    for (int s = 0; s < SS; ++s) wv[s] = cw[c * SS + s];

    // ---- re-stage: identical pattern; x is L3-resident after K1 ----
#pragma unroll
    for (int i = 0; i < 17; ++i) {
        const int r  = wid * 34 + 2 * i + rhalf;
        const int c2 = r - PAD;
        float v = 0.f;
        if (c2 >= 0 && c2 < CC) {
            const int sh = (c2 % SS) - PAD;
            const int t  = t0 + col - sh;
            if (t >= 0 && t < TT) v = xn[c2 * TT + t];
        }
        ls[r * STRIDE + col] = v;
    }
    __syncthreads();

    // ---- conv (bit-identical order to K1) -> res ----
    const int base = c * STRIDE + jb;
    float res[TL / 2];
#pragma unroll
    for (int j = 0; j < TL / 2; ++j) {
        float acc = 0.f;
#pragma unroll
        for (int s = 0; s < SS; ++s)
            acc = fmaf(wv[s], ls[base + s * STRIDE + j], acc);
        res[j] = acc;
    }
    __syncthreads();                      // conv reads done; ls reusable

    // ---- normalize + ReLU -> LDS transpose ----
#pragma unroll
    for (int j = 0; j < TL / 2; ++j) {
        float v = fmaf(res[j], g, b);
        ls[c * STRIDE + jb + j] = v > 0.f ? v : 0.f;
    }
    __syncthreads();

    // ---- coalesced float4 store: 1024 float4 = 128 rows x 8 ----
    float* __restrict__ on = out + (size_t)n * CC * TT + t0;
#pragma unroll
    for (int k = 0; k < 4; ++k) {
        const int f   = tid + 256 * k;
        const int row = f >> 3;
        const int q   = (f & 7) * 4;      // 16B-aligned (t0 mult of 32)
        float4 v;
        v.x = ls[row * STRIDE + q];
        v.y = ls[row * STRIDE + q + 1];
        v.z = ls[row * STRIDE + q + 2];
        v.w = ls[row * STRIDE + q + 3];
        *reinterpret_cast<float4*>(on + (size_t)row * TT + q) = v;
    }
}

extern "C" void kernel_launch(void* const* d_in, const int* in_sizes, int n_in,
                              void* d_out, int out_size, void* d_ws, size_t ws_size,
                              hipStream_t stream)
{
    const float* x     = (const float*)d_in[0];
    const float* cw    = (const float*)d_in[1];
    const float* gamma = (const float*)d_in[2];
    const float* beta  = (const float*)d_in[3];
    float* out     = (float*)d_out;
    float* buckets = (float*)d_ws;        // [NB][2][CC] = 16 KB

    hipMemsetAsync(buckets, 0, (size_t)NB * 2 * CC * sizeof(float), stream);

    dim3 grid(TT / TL, NN);               // 64 x 64 = 4096 blocks
    conv_stats<<<grid, 256, 0, stream>>>(x, cw, buckets);
    conv_norm_store<<<grid, 256, 0, stream>>>(x, cw, buckets, gamma, beta, out);
}

// Round 5
// 147.004 us; speedup vs baseline: 1.0711x; 1.0411x over previous
//
#include <hip/hip_runtime.h>

#define NN 64
#define CC 128
#define TT 2048
#define SS 9
#define PAD 4
#define EPSF 1e-5f
#define TL 32                 // t columns per block
#define ROWS (CC + 2 * PAD)   // 136 staged rows
#define STRIDE (TL + 1)       // 33: odd -> conflict-free c-per-lane conv reads
#define NB 16                 // stat buckets

// ---------------------------------------------------------------------------
// Two-kernel recompute structure (verified R4, 153 us) with VECTORIZED staging:
// float4 global loads (16 B/lane, 8 lanes x float4 per 32-col row) replace the
// 17x scalar-4B-load staging that ran at ~3 TB/s (issue/latency-bound,
// VALUBusy 21%). Edge tiles (t0==0 / t0==2016, block-uniform) take a
// per-component clamped path. LDS writes stay scalar b32: stride-33 keeps conv
// reads conflict-free; staging write conflicts are <=2-way (free, m136).
// Conv / stats / fold / normalize / transpose / store: byte-identical to R4.
// ---------------------------------------------------------------------------
__device__ __forceinline__ void stage_tile(
    const float* __restrict__ xn, float* __restrict__ ls,
    const int t0, const int tid)
{
    const bool interior = (t0 != 0) && (t0 != TT - TL);   // block-uniform
#pragma unroll
    for (int p = 0; p < 5; ++p) {         // 136 rows x 8 lanes = 1088 slots
        const int f = tid + 256 * p;
        const int r = f >> 3;
        if (r < ROWS) {
            const int j0 = (f & 7) * 4;
            const int c2 = r - PAD;
            float4 v = make_float4(0.f, 0.f, 0.f, 0.f);
            if (c2 >= 0 && c2 < CC) {
                const int sh = c2 % SS - PAD;
                const int t  = t0 + j0 - sh;              // 4B-aligned
                const float* __restrict__ row = xn + (size_t)c2 * TT;
                if (interior) {
                    __builtin_memcpy(&v, row + t, sizeof(float4));
                } else {
                    v.x = (t     >= 0 && t     < TT) ? row[t]     : 0.f;
                    v.y = (t + 1 >= 0 && t + 1 < TT) ? row[t + 1] : 0.f;
                    v.z = (t + 2 >= 0 && t + 2 < TT) ? row[t + 2] : 0.f;
                    v.w = (t + 3 >= 0 && t + 3 < TT) ? row[t + 3] : 0.f;
                }
            }
            ls[r * STRIDE + j0]     = v.x;
            ls[r * STRIDE + j0 + 1] = v.y;
            ls[r * STRIDE + j0 + 2] = v.z;
            ls[r * STRIDE + j0 + 3] = v.w;
        }
    }
}

// K1: stage (vectorized) -> conv -> stats atomics only.
__global__ __launch_bounds__(256, 8) void conv_stats(
    const float* __restrict__ x, const float* __restrict__ cw,
    float* __restrict__ buckets)
{
    __shared__ float ls[ROWS * STRIDE];   // 17952 B
    __shared__ float sred[512];           // +2048 B -> 20000 B, 8 blocks/CU

    const int n   = blockIdx.y;
    const int t0  = blockIdx.x * TL;
    const int tid = threadIdx.x;
    const float* __restrict__ xn = x + (size_t)n * CC * TT;

    stage_tile(xn, ls, t0, tid);

    const int c  = tid & (CC - 1);        // fixed output channel per thread
    const int jb = (tid >> 7) * (TL / 2); // 0 or 16
    float wv[SS];
#pragma unroll
    for (int s = 0; s < SS; ++s) wv[s] = cw[c * SS + s];

    __syncthreads();

    // conv: rows c..c+8, conflict-free (STRIDE odd, c = lane)
    const int base = c * STRIDE + jb;
    float s1 = 0.f, s2 = 0.f;
#pragma unroll
    for (int j = 0; j < TL / 2; ++j) {
        float acc = 0.f;
#pragma unroll
        for (int s = 0; s < SS; ++s)
            acc = fmaf(wv[s], ls[base + s * STRIDE + j], acc);
        s1 += acc;
        s2 = fmaf(acc, acc, s2);
    }

    // pair-combine partials -> 1 atomic per (block, channel)
    sred[tid]       = s1;
    sred[256 + tid] = s2;
    __syncthreads();
    if (tid < CC) {
        float* bs = buckets + ((blockIdx.x + blockIdx.y) & (NB - 1)) * 2 * CC;
        atomicAdd(&bs[tid],      sred[tid]       + sred[tid + 128]);
        atomicAdd(&bs[CC + tid], sred[256 + tid] + sred[256 + tid + 128]);
    }
}

// K2: re-stage (L3-resident, vectorized) -> conv -> fold -> norm -> store.
__global__ __launch_bounds__(256, 8) void conv_norm_store(
    const float* __restrict__ x, const float* __restrict__ cw,
    const float* __restrict__ buckets, const float* __restrict__ gamma,
    const float* __restrict__ beta, float* __restrict__ out)
{
    __shared__ float ls[ROWS * STRIDE];   // 17952 B -> 8 blocks/CU

    const int n   = blockIdx.y;
    const int t0  = blockIdx.x * TL;
    const int tid = threadIdx.x;
    const float* __restrict__ xn = x + (size_t)n * CC * TT;

    const int c  = tid & (CC - 1);
    const int jb = (tid >> 7) * (TL / 2);

    // fold 16 buckets (L2-resident 16 KB, coalesced) -> per-thread g,b
    float t1 = 0.f, t2 = 0.f;
#pragma unroll
    for (int k = 0; k < NB; ++k) {
        t1 += buckets[k * 2 * CC + c];
        t2 += buckets[k * 2 * CC + CC + c];
    }
    const float inv_cnt = 1.0f / (float)(NN * TT);
    const float mean = t1 * inv_cnt;
    const float var  = t2 * inv_cnt - mean * mean;
    const float inv  = rsqrtf(var + EPSF);
    const float g = gamma[c] * inv;
    const float b = beta[c] - mean * g;

    float wv[SS];
#pragma unroll
    for (int s = 0; s < SS; ++s) wv[s] = cw[c * SS + s];

    stage_tile(xn, ls, t0, tid);
    __syncthreads();

    // conv (bit-identical order to K1) -> res
    const int base = c * STRIDE + jb;
    float res[TL / 2];
#pragma unroll
    for (int j = 0; j < TL / 2; ++j) {
        float acc = 0.f;
#pragma unroll
        for (int s = 0; s < SS; ++s)
            acc = fmaf(wv[s], ls[base + s * STRIDE + j], acc);
        res[j] = acc;
    }
    __syncthreads();                      // conv reads done; ls reusable

    // normalize + ReLU -> LDS transpose
#pragma unroll
    for (int j = 0; j < TL / 2; ++j) {
        float v = fmaf(res[j], g, b);
        ls[c * STRIDE + jb + j] = v > 0.f ? v : 0.f;
    }
    __syncthreads();

    // coalesced float4 store: 1024 float4 = 128 rows x 8
    float* __restrict__ on = out + (size_t)n * CC * TT + t0;
#pragma unroll
    for (int k = 0; k < 4; ++k) {
        const int f   = tid + 256 * k;
        const int row = f >> 3;
        const int q   = (f & 7) * 4;      // 16B-aligned (t0 mult of 32)
        float4 v;
        v.x = ls[row * STRIDE + q];
        v.y = ls[row * STRIDE + q + 1];
        v.z = ls[row * STRIDE + q + 2];
        v.w = ls[row * STRIDE + q + 3];
        *reinterpret_cast<float4*>(on + (size_t)row * TT + q) = v;
    }
}

extern "C" void kernel_launch(void* const* d_in, const int* in_sizes, int n_in,
                              void* d_out, int out_size, void* d_ws, size_t ws_size,
                              hipStream_t stream)
{
    const float* x     = (const float*)d_in[0];
    const float* cw    = (const float*)d_in[1];
    const float* gamma = (const float*)d_in[2];
    const float* beta  = (const float*)d_in[3];
    float* out     = (float*)d_out;
    float* buckets = (float*)d_ws;        // [NB][2][CC] = 16 KB

    hipMemsetAsync(buckets, 0, (size_t)NB * 2 * CC * sizeof(float), stream);

    dim3 grid(TT / TL, NN);               // 64 x 64 = 4096 blocks
    conv_stats<<<grid, 256, 0, stream>>>(x, cw, buckets);
    conv_norm_store<<<grid, 256, 0, stream>>>(x, cw, buckets, gamma, beta, out);
}